// Round 1
// baseline (375.094 us; speedup 1.0000x reference)
//
#include <hip/hip_runtime.h>
#include <hip/hip_bf16.h>
#include <math.h>

#define N_NODES 50000
#define DEG     32
#define T       4
#define KP      160      // folded posttrans K: 32 (ht) + 128 (agg)
#define NB3     25       // nodes per block in K3/K4 (50000 = 2000*25)
#define EPSV    1e-5f

// ---------- K1: fold scalers into posttrans weights ----------
// Weff[t][k][o]: k<32 -> W_post rows 0..31 (ht part);
// k in 32..159 -> W1 + sc*W2 + inv_sc*W3 (agg/amp/att folded, deg==32 const)
__global__ void k_weff(const float* __restrict__ W_post, float* __restrict__ Weff,
                       float sc, float inv_sc) {
    int i = blockIdx.x * 256 + threadIdx.x;     // over T*KP*32 = 20480
    if (i >= T * KP * 32) return;
    int o = i & 31;
    int k = (i >> 5) % KP;
    int t = i / (KP * 32);
    const float* Wt = W_post + t * 416 * 32;
    float v;
    if (k < 32) {
        v = Wt[k * 32 + o];
    } else {
        int g = k - 32;                          // 0..127 over [mean,mx,mn,std]
        v = Wt[(32 + g) * 32 + o]
          + sc * Wt[(160 + g) * 32 + o]
          + inv_sc * Wt[(288 + g) * 32 + o];
    }
    Weff[i] = v;
}

// ---------- K2: per-node projections Ps (src half, bf16) / Pd (dst half + b_pre, f32) ----------
__global__ __launch_bounds__(128) void k_proj(const float* __restrict__ h,
        const float* __restrict__ W_pre, const float* __restrict__ b_pre,
        float* __restrict__ Pd, __hip_bfloat16* __restrict__ Ps) {
    int n = blockIdx.x;
    int c = threadIdx.x;            // 0..127 channel
    int t = c >> 5, o = c & 31;
    __shared__ float sh[128];
    sh[c] = h[n * 128 + c];
    __syncthreads();
    const float* Wt = W_pre + t * 64 * 32;
    float as = 0.f, ad = 0.f;
#pragma unroll
    for (int k = 0; k < 32; ++k) {
        float hv = sh[t * 32 + k];
        as = fmaf(hv, Wt[k * 32 + o], as);          // src half: rows 0..31
        ad = fmaf(hv, Wt[(32 + k) * 32 + o], ad);   // dst half: rows 32..63
    }
    Pd[n * 128 + c] = ad + b_pre[t * 32 + o];
    Ps[n * 128 + c] = __float2bfloat16(as);
}

// ---------- K3: per-node aggregation stats + folded posttrans ----------
// block = 128 threads (thread owns channel c), NB3 nodes sequentially,
// Weff column register-cached (160 VGPRs) and reused across nodes.
__global__ __launch_bounds__(128) void k_agg_post(
        const float* __restrict__ h, const int* __restrict__ src,
        const float* __restrict__ Pd, const __hip_bfloat16* __restrict__ Ps,
        const float* __restrict__ Weff, const float* __restrict__ b_post,
        float* __restrict__ hcat) {
    int c = threadIdx.x, t = c >> 5, o = c & 31;
    int base = blockIdx.x * NB3;
    __shared__ float sZ[T * KP];     // [t][160]: ht | mean | max | min | std
    __shared__ int sSrc[DEG];
    float w[KP];
#pragma unroll
    for (int k = 0; k < KP; ++k) w[k] = Weff[(t * KP + k) * 32 + o];
    float bp = b_post[t * 32 + o];

    for (int ni = 0; ni < NB3; ++ni) {
        int n = base + ni;
        if (c < DEG) sSrc[c] = src[n * DEG + c];
        __syncthreads();
        float pd = Pd[n * 128 + c];
        float hv = h[n * 128 + c];
        float sum = 0.f, sq = 0.f, mx = -1e30f, mn = 1e30f;
#pragma unroll
        for (int j0 = 0; j0 < DEG; j0 += 8) {
            float v[8];
#pragma unroll
            for (int u = 0; u < 8; ++u) {
                int s = __builtin_amdgcn_readfirstlane(sSrc[j0 + u]);
                v[u] = __bfloat162float(Ps[s * 128 + c]);
            }
#pragma unroll
            for (int u = 0; u < 8; ++u) {
                float e = fmaxf(v[u] + pd, 0.f);
                sum += e;
                sq = fmaf(e, e, sq);
                mx = fmaxf(mx, e);
                mn = fminf(mn, e);
            }
        }
        float mean = sum * (1.f / DEG);
        float msq  = sq  * (1.f / DEG);
        float var  = msq - mean * mean;
        float sd   = sqrtf(fmaxf(var, 0.f) + EPSV);
        sZ[t * KP +       o] = hv;
        sZ[t * KP +  32 + o] = mean;
        sZ[t * KP +  64 + o] = mx;
        sZ[t * KP +  96 + o] = mn;
        sZ[t * KP + 128 + o] = sd;
        __syncthreads();
        float a0 = 0.f, a1 = 0.f, a2 = 0.f, a3 = 0.f;
        const float4* z4 = (const float4*)(sZ + t * KP);   // KP%4==0, aligned
#pragma unroll
        for (int k = 0; k < KP; k += 4) {
            float4 zz = z4[k >> 2];
            a0 = fmaf(zz.x, w[k + 0], a0);
            a1 = fmaf(zz.y, w[k + 1], a1);
            a2 = fmaf(zz.z, w[k + 2], a2);
            a3 = fmaf(zz.w, w[k + 3], a3);
        }
        hcat[n * 128 + c] = fmaxf((a0 + a1) + (a2 + a3) + bp, 0.f);
    }
}

// ---------- K4: mixing network + residual ----------
__global__ __launch_bounds__(128) void k_mix(
        const float* __restrict__ h, const float* __restrict__ hcat,
        const float* __restrict__ W_mix, const float* __restrict__ b_mix,
        float* __restrict__ out) {
    int c = threadIdx.x;
    int base = blockIdx.x * NB3;
    __shared__ float sH[128];
    float w[128];
#pragma unroll
    for (int k = 0; k < 128; ++k) w[k] = W_mix[k * 128 + c];
    float bm = b_mix[c];
    for (int ni = 0; ni < NB3; ++ni) {
        int n = base + ni;
        sH[c] = hcat[n * 128 + c];
        __syncthreads();
        float a0 = 0.f, a1 = 0.f, a2 = 0.f, a3 = 0.f;
        const float4* h4 = (const float4*)sH;
#pragma unroll
        for (int k = 0; k < 128; k += 4) {
            float4 zz = h4[k >> 2];
            a0 = fmaf(zz.x, w[k + 0], a0);
            a1 = fmaf(zz.y, w[k + 1], a1);
            a2 = fmaf(zz.z, w[k + 2], a2);
            a3 = fmaf(zz.w, w[k + 3], a3);
        }
        float m = (a0 + a1) + (a2 + a3) + bm;
        out[n * 128 + c] = h[n * 128 + c] + (m > 0.f ? m : 0.01f * m);
        __syncthreads();   // protect sH before next node's stage
    }
}

extern "C" void kernel_launch(void* const* d_in, const int* in_sizes, int n_in,
                              void* d_out, int out_size, void* d_ws, size_t ws_size,
                              hipStream_t stream) {
    const float* h      = (const float*)d_in[0];
    const int*   src    = (const int*)d_in[1];
    // d_in[2] = dst: structurally repeat(arange(N), DEG) -> unused
    const float* W_pre  = (const float*)d_in[3];
    const float* b_pre  = (const float*)d_in[4];
    const float* W_post = (const float*)d_in[5];
    const float* b_post = (const float*)d_in[6];
    const float* W_mix  = (const float*)d_in[7];
    const float* b_mix  = (const float*)d_in[8];
    float* out = (float*)d_out;

    char* ws = (char*)d_ws;
    float*          Weff = (float*)ws;                                   // 20480 f32
    float*          Pd   = (float*)(ws + 81920);                         // 6.4e6 f32
    __hip_bfloat16* Ps   = (__hip_bfloat16*)(ws + 81920 + 25600000);     // 6.4e6 bf16
    float*          hcat = (float*)(ws + 81920 + 25600000 + 12800000);   // 6.4e6 f32

    double scd = log(33.0) / log(5.0);    // deg==32 constant -> scaler constant
    float sc = (float)scd;
    float inv_sc = (float)(1.0 / scd);    // max(sc, 1e-5) == sc

    hipLaunchKernelGGL(k_weff, dim3(80), dim3(256), 0, stream, W_post, Weff, sc, inv_sc);
    hipLaunchKernelGGL(k_proj, dim3(N_NODES), dim3(128), 0, stream, h, W_pre, b_pre, Pd, Ps);
    hipLaunchKernelGGL(k_agg_post, dim3(N_NODES / NB3), dim3(128), 0, stream,
                       h, src, Pd, Ps, Weff, b_post, hcat);
    hipLaunchKernelGGL(k_mix, dim3(N_NODES / NB3), dim3(128), 0, stream,
                       h, hcat, W_mix, b_mix, out);
}

// Round 2
// 246.596 us; speedup vs baseline: 1.5211x; 1.5211x over previous
//
#include <hip/hip_runtime.h>
#include <hip/hip_bf16.h>
#include <math.h>

#define N_NODES 50000
#define DEG     32
#define NBP     25       // nodes/block k_proj
#define NBA     10       // nodes/block k_agg
#define EPSV    1e-5f

typedef __attribute__((ext_vector_type(8))) short short8;   // 8 bf16 (4 VGPRs)
typedef __attribute__((ext_vector_type(4))) float f32x4;
typedef __attribute__((ext_vector_type(4))) int  int4v;

// ---------- K0: fold scalers, transpose, cast weights to bf16 ----------
// WeffT[t][o][k] (k:160), WmixT[o][k] (k:128)
__global__ void k_prep(const float* __restrict__ W_post, const float* __restrict__ W_mix,
                       __hip_bfloat16* __restrict__ WeffT, __hip_bfloat16* __restrict__ WmixT,
                       float sc, float isc) {
    int i = blockIdx.x * 256 + threadIdx.x;
    if (i < 4 * 32 * 160) {
        int k = i % 160, to = i / 160, o = to & 31, t = to >> 5;
        const float* Wt = W_post + t * 416 * 32;
        float v;
        if (k < 32) v = Wt[k * 32 + o];
        else {
            int g = k - 32;   // [mean,mx,mn,std] block; fold identity+amp+att
            v = Wt[(32 + g) * 32 + o] + sc * Wt[(160 + g) * 32 + o] + isc * Wt[(288 + g) * 32 + o];
        }
        WeffT[i] = __float2bfloat16(v);
    }
    int j = i - 4 * 32 * 160;
    if (j >= 0 && j < 128 * 128) {
        int k = j & 127, o = j >> 7;
        WmixT[j] = __float2bfloat16(W_mix[k * 128 + o]);
    }
}

// ---------- K1: per-node pretrans projections, weights register-resident ----------
__global__ __launch_bounds__(128) void k_proj(const float* __restrict__ h,
        const float* __restrict__ W_pre, const float* __restrict__ b_pre,
        __hip_bfloat16* __restrict__ Pd, __hip_bfloat16* __restrict__ Ps) {
    int c = threadIdx.x, t = c >> 5, o = c & 31;
    const float* Wt = W_pre + t * 64 * 32;
    float wsr[32], wdr[32];
#pragma unroll
    for (int k = 0; k < 32; ++k) { wsr[k] = Wt[k * 32 + o]; wdr[k] = Wt[(32 + k) * 32 + o]; }
    float bp = b_pre[t * 32 + o];
    __shared__ float sh[128];
    int base = blockIdx.x * NBP;
    for (int ni = 0; ni < NBP; ++ni) {
        int n = base + ni;
        __syncthreads();
        sh[c] = h[n * 128 + c];
        __syncthreads();
        const float4* h4 = (const float4*)(sh + t * 32);
        float as = 0.f, ad = 0.f;
#pragma unroll
        for (int k4 = 0; k4 < 8; ++k4) {
            float4 hv = h4[k4];
            as = fmaf(hv.x, wsr[4*k4+0], as); ad = fmaf(hv.x, wdr[4*k4+0], ad);
            as = fmaf(hv.y, wsr[4*k4+1], as); ad = fmaf(hv.y, wdr[4*k4+1], ad);
            as = fmaf(hv.z, wsr[4*k4+2], as); ad = fmaf(hv.z, wdr[4*k4+2], ad);
            as = fmaf(hv.w, wsr[4*k4+3], as); ad = fmaf(hv.w, wdr[4*k4+3], ad);
        }
        Ps[n * 128 + c] = __float2bfloat16(as);
        Pd[n * 128 + c] = __float2bfloat16(ad + bp);
    }
}

// ---------- K2: gather + aggregation stats -> z bf16 [N][640] ----------
// z row per node: per tower t: [ht(32) | mean(32) | mx(32) | mn(32) | std(32)]
__global__ __launch_bounds__(128) void k_agg(const float* __restrict__ h,
        const int* __restrict__ src, const __hip_bfloat16* __restrict__ Pd,
        const __hip_bfloat16* __restrict__ Ps, __hip_bfloat16* __restrict__ Z) {
    int c = threadIdx.x, t = c >> 5, o = c & 31;
    __shared__ int sSrc[DEG];
    int base = blockIdx.x * NBA;
    for (int ni = 0; ni < NBA; ++ni) {
        int n = base + ni;
        __syncthreads();
        if (c < DEG) sSrc[c] = src[n * DEG + c];
        __syncthreads();
        float pd = __bfloat162float(Pd[n * 128 + c]);
        float hv = h[n * 128 + c];
        float sum = 0.f, sq = 0.f, mx = -1e30f, mn = 1e30f;
#pragma unroll
        for (int j0 = 0; j0 < DEG; j0 += 8) {
            float v[8];
#pragma unroll
            for (int u = 0; u < 8; ++u) {
                int s = __builtin_amdgcn_readfirstlane(sSrc[j0 + u]);
                v[u] = __bfloat162float(Ps[s * 128 + c]);
            }
#pragma unroll
            for (int u = 0; u < 8; ++u) {
                float e = fmaxf(v[u] + pd, 0.f);
                sum += e; sq = fmaf(e, e, sq);
                mx = fmaxf(mx, e); mn = fminf(mn, e);
            }
        }
        float mean = sum * (1.f / DEG);
        float var  = sq * (1.f / DEG) - mean * mean;
        float sd   = sqrtf(fmaxf(var, 0.f) + EPSV);
        __hip_bfloat16* zr = Z + n * 640 + t * 160;
        zr[o]       = __float2bfloat16(hv);
        zr[32 + o]  = __float2bfloat16(mean);
        zr[64 + o]  = __float2bfloat16(mx);
        zr[96 + o]  = __float2bfloat16(mn);
        zr[128 + o] = __float2bfloat16(sd);
    }
}

// ---------- K3: MFMA posttrans + mix + residual, 32 nodes/block, 2 waves ----------
__global__ __launch_bounds__(128) void k_post_mix(const float* __restrict__ h,
        const __hip_bfloat16* __restrict__ Z, const __hip_bfloat16* __restrict__ WeffT,
        const __hip_bfloat16* __restrict__ WmixT, const float* __restrict__ b_post,
        const float* __restrict__ b_mix, float* __restrict__ out) {
    // row pads (+8 / +8) shift consecutive rows by 4 banks -> only 2-way aliasing (free)
    __shared__ __align__(16) __hip_bfloat16 sZ[32][648];
    __shared__ __align__(16) __hip_bfloat16 sHp[32][136];
    int tid = threadIdx.x;
    int w = tid >> 6, lane = tid & 63;
    int col = lane & 15, quad = lane >> 4;
    int nb = blockIdx.x * 32;

    // cooperative z stage: 32 rows x 80 16B-chunks = 2560 chunks / 128 thr
#pragma unroll
    for (int i = 0; i < 20; ++i) {
        int chunk = tid + 128 * i;
        int row = chunk / 80, off = chunk % 80;
        int n = nb + row;
        if (n < N_NODES)
            *(int4v*)(&sZ[row][off * 8]) = *(const int4v*)(Z + n * 640 + off * 8);
    }
    __syncthreads();

    int r0 = w * 16;      // this wave's 16 node rows
    // posttrans: 4 towers x 2 N-tiles x 5 K-steps
#pragma unroll
    for (int t = 0; t < 4; ++t) {
#pragma unroll
        for (int nt = 0; nt < 2; ++nt) {
            f32x4 acc = {0.f, 0.f, 0.f, 0.f};
            const __hip_bfloat16* wrow = WeffT + (t * 32 + nt * 16 + col) * 160 + quad * 8;
#pragma unroll
            for (int ks = 0; ks < 5; ++ks) {
                short8 a = *(const short8*)(&sZ[r0 + col][t * 160 + ks * 32 + quad * 8]);
                short8 b = *(const short8*)(wrow + ks * 32);
                acc = __builtin_amdgcn_mfma_f32_16x16x32_bf16(a, b, acc, 0, 0, 0);
            }
            int oc = t * 32 + nt * 16 + col;
            float bp = b_post[oc];
#pragma unroll
            for (int r = 0; r < 4; ++r) {
                float v = acc[r] + bp;
                sHp[r0 + quad * 4 + r][oc] = __float2bfloat16(fmaxf(v, 0.f));
            }
        }
    }
    __syncthreads();
    // mix: 8 N-tiles x 4 K-steps, then leaky + residual
#pragma unroll
    for (int nt = 0; nt < 8; ++nt) {
        f32x4 acc = {0.f, 0.f, 0.f, 0.f};
        const __hip_bfloat16* wrow = WmixT + (nt * 16 + col) * 128 + quad * 8;
#pragma unroll
        for (int ks = 0; ks < 4; ++ks) {
            short8 a = *(const short8*)(&sHp[r0 + col][ks * 32 + quad * 8]);
            short8 b = *(const short8*)(wrow + ks * 32);
            acc = __builtin_amdgcn_mfma_f32_16x16x32_bf16(a, b, acc, 0, 0, 0);
        }
        int oc = nt * 16 + col;
        float bm = b_mix[oc];
#pragma unroll
        for (int r = 0; r < 4; ++r) {
            int n = nb + r0 + quad * 4 + r;
            if (n < N_NODES) {
                float m = acc[r] + bm;
                m = m > 0.f ? m : 0.01f * m;
                out[n * 128 + oc] = h[n * 128 + oc] + m;
            }
        }
    }
}

extern "C" void kernel_launch(void* const* d_in, const int* in_sizes, int n_in,
                              void* d_out, int out_size, void* d_ws, size_t ws_size,
                              hipStream_t stream) {
    const float* h      = (const float*)d_in[0];
    const int*   src    = (const int*)d_in[1];
    // d_in[2] = dst: structurally repeat(arange(N), DEG) -> unused
    const float* W_pre  = (const float*)d_in[3];
    const float* b_pre  = (const float*)d_in[4];
    const float* W_post = (const float*)d_in[5];
    const float* b_post = (const float*)d_in[6];
    const float* W_mix  = (const float*)d_in[7];
    const float* b_mix  = (const float*)d_in[8];
    float* out = (float*)d_out;

    char* ws = (char*)d_ws;
    __hip_bfloat16* WeffT = (__hip_bfloat16*)ws;                          // 20480 bf16
    __hip_bfloat16* WmixT = (__hip_bfloat16*)(ws + 40960);                // 16384 bf16
    __hip_bfloat16* Pd    = (__hip_bfloat16*)(ws + 73728);                // N*128
    __hip_bfloat16* Ps    = (__hip_bfloat16*)(ws + 73728 + 12800000);     // N*128
    __hip_bfloat16* Z     = (__hip_bfloat16*)(ws + 73728 + 25600000);     // N*640

    double scd = log(33.0) / log(5.0);    // deg==32 constant
    float sc = (float)scd, isc = (float)(1.0 / scd);

    hipLaunchKernelGGL(k_prep, dim3(144), dim3(256), 0, stream, W_post, W_mix, WeffT, WmixT, sc, isc);
    hipLaunchKernelGGL(k_proj, dim3(N_NODES / NBP), dim3(128), 0, stream, h, W_pre, b_pre, Pd, Ps);
    hipLaunchKernelGGL(k_agg, dim3(N_NODES / NBA), dim3(128), 0, stream, h, src, Pd, Ps, Z);
    hipLaunchKernelGGL(k_post_mix, dim3((N_NODES + 31) / 32), dim3(128), 0, stream,
                       h, Z, WeffT, WmixT, b_post, b_mix, out);
}

// Round 3
// 198.857 us; speedup vs baseline: 1.8863x; 1.2401x over previous
//
#include <hip/hip_runtime.h>
#include <hip/hip_bf16.h>
#include <math.h>

#define N_NODES 50000
#define DEG     32
#define NBP     25       // nodes/block k_proj
#define EPSV    1e-5f

typedef __attribute__((ext_vector_type(8))) short short8;   // 8 bf16 (4 VGPRs)
typedef __attribute__((ext_vector_type(4))) float f32x4;

// ---------- K0: fold scalers, transpose, cast weights to bf16 ----------
// WeffT[t][o][k] (k:160), WmixT[o][k] (k:128)
__global__ void k_prep(const float* __restrict__ W_post, const float* __restrict__ W_mix,
                       __hip_bfloat16* __restrict__ WeffT, __hip_bfloat16* __restrict__ WmixT,
                       float sc, float isc) {
    int i = blockIdx.x * 256 + threadIdx.x;
    if (i < 4 * 32 * 160) {
        int k = i % 160, to = i / 160, o = to & 31, t = to >> 5;
        const float* Wt = W_post + t * 416 * 32;
        float v;
        if (k < 32) v = Wt[k * 32 + o];
        else {
            int g = k - 32;   // [mean,mx,mn,std]; fold identity+amp+att (deg==32 const)
            v = Wt[(32 + g) * 32 + o] + sc * Wt[(160 + g) * 32 + o] + isc * Wt[(288 + g) * 32 + o];
        }
        WeffT[i] = __float2bfloat16(v);
    }
    int j = i - 4 * 32 * 160;
    if (j >= 0 && j < 128 * 128) {
        int k = j & 127, o = j >> 7;
        WmixT[j] = __float2bfloat16(W_mix[k * 128 + o]);
    }
}

// ---------- K1: per-node pretrans projections, weights register-resident ----------
__global__ __launch_bounds__(128) void k_proj(const float* __restrict__ h,
        const float* __restrict__ W_pre, const float* __restrict__ b_pre,
        __hip_bfloat16* __restrict__ Pd, __hip_bfloat16* __restrict__ Ps) {
    int c = threadIdx.x, t = c >> 5, o = c & 31;
    const float* Wt = W_pre + t * 64 * 32;
    float wsr[32], wdr[32];
#pragma unroll
    for (int k = 0; k < 32; ++k) { wsr[k] = Wt[k * 32 + o]; wdr[k] = Wt[(32 + k) * 32 + o]; }
    float bp = b_pre[t * 32 + o];
    __shared__ float sh[128];
    int base = blockIdx.x * NBP;
    for (int ni = 0; ni < NBP; ++ni) {
        int n = base + ni;
        __syncthreads();
        sh[c] = h[n * 128 + c];
        __syncthreads();
        const float4* h4 = (const float4*)(sh + t * 32);
        float as = 0.f, ad = 0.f;
#pragma unroll
        for (int k4 = 0; k4 < 8; ++k4) {
            float4 hv = h4[k4];
            as = fmaf(hv.x, wsr[4*k4+0], as); ad = fmaf(hv.x, wdr[4*k4+0], ad);
            as = fmaf(hv.y, wsr[4*k4+1], as); ad = fmaf(hv.y, wdr[4*k4+1], ad);
            as = fmaf(hv.z, wsr[4*k4+2], as); ad = fmaf(hv.z, wdr[4*k4+2], ad);
            as = fmaf(hv.w, wsr[4*k4+3], as); ad = fmaf(hv.w, wdr[4*k4+3], ad);
        }
        Ps[n * 128 + c] = __float2bfloat16(as);
        Pd[n * 128 + c] = __float2bfloat16(ad + bp);
    }
}

// ---------- K2: fused gather+stats -> LDS z -> MFMA posttrans+mix+residual ----------
// 32 nodes/block, 256 threads (4 waves). Stats: wave w owns node (round*4+w),
// lane owns 2 channels (one 4B gather load per edge). z never leaves LDS.
__global__ __launch_bounds__(256) void k_fused(const float* __restrict__ h,
        const int* __restrict__ src, const __hip_bfloat16* __restrict__ Pd,
        const __hip_bfloat16* __restrict__ Ps, const __hip_bfloat16* __restrict__ WeffT,
        const __hip_bfloat16* __restrict__ WmixT, const float* __restrict__ b_post,
        const float* __restrict__ b_mix, float* __restrict__ out) {
    // row pads (+8) shift rows by 4 banks; 16-row MFMA reads alias 2-way (free)
    __shared__ __align__(16) __hip_bfloat16 sZ[32][648];
    __shared__ __align__(16) __hip_bfloat16 sHp[32][136];
    int tid = threadIdx.x, w = tid >> 6, lane = tid & 63;
    int nb = blockIdx.x * 32;

    // ---- Phase A: aggregation stats straight into sZ ----
    int c0 = 2 * lane;                 // this lane's channel pair
    int tA = c0 >> 5, oA = c0 & 31;    // tower / within-tower offset (even)
#pragma unroll
    for (int r = 0; r < 8; ++r) {
        int row = r * 4 + w;
        int n = nb + row;
        __hip_bfloat16* zr = &sZ[row][tA * 160 + oA];
        if (n < N_NODES) {             // wave-uniform branch
            int vsrc = src[n * DEG + (lane & 31)];      // lanes 32-63 duplicate 0-31
            float2 hv = *(const float2*)(h + n * 128 + c0);
            unsigned int pdu = *(const unsigned int*)(Pd + n * 128 + c0);
            float pd0 = __uint_as_float(pdu << 16);
            float pd1 = __uint_as_float(pdu & 0xffff0000u);
            float sum0 = 0.f, sum1 = 0.f, sq0 = 0.f, sq1 = 0.f;
            float mx0 = -1e30f, mx1 = -1e30f, mn0 = 1e30f, mn1 = 1e30f;
#pragma unroll
            for (int j0 = 0; j0 < DEG; j0 += 8) {
                unsigned int pv[8];
#pragma unroll
                for (int u = 0; u < 8; ++u) {
                    int s = __builtin_amdgcn_readlane(vsrc, j0 + u);
                    pv[u] = *(const unsigned int*)(Ps + s * 128 + c0);
                }
#pragma unroll
                for (int u = 0; u < 8; ++u) {
                    float f0 = __uint_as_float(pv[u] << 16);
                    float f1 = __uint_as_float(pv[u] & 0xffff0000u);
                    float e0 = fmaxf(f0 + pd0, 0.f);
                    float e1 = fmaxf(f1 + pd1, 0.f);
                    sum0 += e0; sq0 = fmaf(e0, e0, sq0);
                    mx0 = fmaxf(mx0, e0); mn0 = fminf(mn0, e0);
                    sum1 += e1; sq1 = fmaf(e1, e1, sq1);
                    mx1 = fmaxf(mx1, e1); mn1 = fminf(mn1, e1);
                }
            }
            float mean0 = sum0 * (1.f / DEG), mean1 = sum1 * (1.f / DEG);
            float sd0 = sqrtf(fmaxf(sq0 * (1.f / DEG) - mean0 * mean0, 0.f) + EPSV);
            float sd1 = sqrtf(fmaxf(sq1 * (1.f / DEG) - mean1 * mean1, 0.f) + EPSV);
            zr[0]   = __float2bfloat16(hv.x);  zr[1]   = __float2bfloat16(hv.y);
            zr[32]  = __float2bfloat16(mean0); zr[33]  = __float2bfloat16(mean1);
            zr[64]  = __float2bfloat16(mx0);   zr[65]  = __float2bfloat16(mx1);
            zr[96]  = __float2bfloat16(mn0);   zr[97]  = __float2bfloat16(mn1);
            zr[128] = __float2bfloat16(sd0);   zr[129] = __float2bfloat16(sd1);
        } else {
            *(unsigned int*)(zr)       = 0u; *(unsigned int*)(zr + 32) = 0u;
            *(unsigned int*)(zr + 64)  = 0u; *(unsigned int*)(zr + 96) = 0u;
            *(unsigned int*)(zr + 128) = 0u;
        }
    }
    __syncthreads();

    // ---- Phase B: posttrans MFMA (8 col-tiles x 2 row-tiles over 4 waves) ----
    int col = lane & 15, quad = lane >> 4;
    int r0 = (w & 1) * 16;
    int ctb = (w >> 1) * 4;
#pragma unroll
    for (int i = 0; i < 4; ++i) {
        int ct = ctb + i, t = ct >> 1, nt = ct & 1;
        f32x4 acc = {0.f, 0.f, 0.f, 0.f};
        int oc = t * 32 + nt * 16 + col;
        const __hip_bfloat16* wrow = WeffT + oc * 160 + quad * 8;
#pragma unroll
        for (int ks = 0; ks < 5; ++ks) {
            short8 a = *(const short8*)(&sZ[r0 + col][t * 160 + ks * 32 + quad * 8]);
            short8 b = *(const short8*)(wrow + ks * 32);
            acc = __builtin_amdgcn_mfma_f32_16x16x32_bf16(a, b, acc, 0, 0, 0);
        }
        float bp = b_post[oc];
#pragma unroll
        for (int r = 0; r < 4; ++r)
            sHp[r0 + quad * 4 + r][oc] = __float2bfloat16(fmaxf(acc[r] + bp, 0.f));
    }
    __syncthreads();

    // ---- Phase C: mix MFMA + leaky ReLU + residual ----
#pragma unroll
    for (int i = 0; i < 4; ++i) {
        int nt = ctb + i;
        f32x4 acc = {0.f, 0.f, 0.f, 0.f};
        int oc = nt * 16 + col;
        const __hip_bfloat16* wrow = WmixT + oc * 128 + quad * 8;
#pragma unroll
        for (int ks = 0; ks < 4; ++ks) {
            short8 a = *(const short8*)(&sHp[r0 + col][ks * 32 + quad * 8]);
            short8 b = *(const short8*)(wrow + ks * 32);
            acc = __builtin_amdgcn_mfma_f32_16x16x32_bf16(a, b, acc, 0, 0, 0);
        }
        float bm = b_mix[oc];
#pragma unroll
        for (int r = 0; r < 4; ++r) {
            int n = nb + r0 + quad * 4 + r;
            if (n < N_NODES) {
                float m = acc[r] + bm;
                m = m > 0.f ? m : 0.01f * m;
                out[n * 128 + oc] = h[n * 128 + oc] + m;
            }
        }
    }
}

extern "C" void kernel_launch(void* const* d_in, const int* in_sizes, int n_in,
                              void* d_out, int out_size, void* d_ws, size_t ws_size,
                              hipStream_t stream) {
    const float* h      = (const float*)d_in[0];
    const int*   src    = (const int*)d_in[1];
    // d_in[2] = dst: structurally repeat(arange(N), DEG) -> unused
    const float* W_pre  = (const float*)d_in[3];
    const float* b_pre  = (const float*)d_in[4];
    const float* W_post = (const float*)d_in[5];
    const float* b_post = (const float*)d_in[6];
    const float* W_mix  = (const float*)d_in[7];
    const float* b_mix  = (const float*)d_in[8];
    float* out = (float*)d_out;

    char* ws = (char*)d_ws;
    __hip_bfloat16* WeffT = (__hip_bfloat16*)ws;                      // 20480 bf16
    __hip_bfloat16* WmixT = (__hip_bfloat16*)(ws + 40960);            // 16384 bf16
    __hip_bfloat16* Pd    = (__hip_bfloat16*)(ws + 73728);            // N*128
    __hip_bfloat16* Ps    = (__hip_bfloat16*)(ws + 73728 + 12800000); // N*128

    double scd = log(33.0) / log(5.0);    // deg==32 constant
    float sc = (float)scd, isc = (float)(1.0 / scd);

    hipLaunchKernelGGL(k_prep, dim3(144), dim3(256), 0, stream, W_post, W_mix, WeffT, WmixT, sc, isc);
    hipLaunchKernelGGL(k_proj, dim3(N_NODES / NBP), dim3(128), 0, stream, h, W_pre, b_pre, Pd, Ps);
    hipLaunchKernelGGL(k_fused, dim3((N_NODES + 31) / 32), dim3(256), 0, stream,
                       h, src, Pd, Ps, WeffT, WmixT, b_post, b_mix, out);
}

// Round 4
// 178.588 us; speedup vs baseline: 2.1003x; 1.1135x over previous
//
#include <hip/hip_runtime.h>
#include <hip/hip_bf16.h>
#include <math.h>

#define N_NODES 50000
#define DEG     32
#define NBP     40       // nodes/block k_proj (50000 = 1250*40)
#define NBF     16       // nodes/block k_fused (50000 = 3125*16)
#define EPSV    1e-5f

typedef __attribute__((ext_vector_type(8))) short short8;   // 8 bf16 (4 VGPRs)
typedef __attribute__((ext_vector_type(4))) float f32x4;

// ---------- K0: fold scalers, transpose, cast weights to bf16 ----------
// WeffT[t][o][k] (k:160), WmixT[o][k] (k:128)
__global__ void k_prep(const float* __restrict__ W_post, const float* __restrict__ W_mix,
                       __hip_bfloat16* __restrict__ WeffT, __hip_bfloat16* __restrict__ WmixT,
                       float sc, float isc) {
    int i = blockIdx.x * 256 + threadIdx.x;
    if (i < 4 * 32 * 160) {
        int k = i % 160, to = i / 160, o = to & 31, t = to >> 5;
        const float* Wt = W_post + t * 416 * 32;
        float v;
        if (k < 32) v = Wt[k * 32 + o];
        else {
            int g = k - 32;   // [mean,mx,mn,std]; fold identity+amp+att (deg==32 const)
            v = Wt[(32 + g) * 32 + o] + sc * Wt[(160 + g) * 32 + o] + isc * Wt[(288 + g) * 32 + o];
        }
        WeffT[i] = __float2bfloat16(v);
    }
    int j = i - 4 * 32 * 160;
    if (j >= 0 && j < 128 * 128) {
        int k = j & 127, o = j >> 7;
        WmixT[j] = __float2bfloat16(W_mix[k * 128 + o]);
    }
}

// ---------- K1: pretrans projections; 256 thr, halves own src/dst proj ----------
__global__ __launch_bounds__(256) void k_proj(const float* __restrict__ h,
        const float* __restrict__ W_pre, const float* __restrict__ b_pre,
        __hip_bfloat16* __restrict__ Pd, __hip_bfloat16* __restrict__ Ps) {
    int tid = threadIdx.x;
    int c = tid & 127, half = tid >> 7;      // half: 0=src-proj(Ps), 1=dst-proj(Pd)
    int t = c >> 5, o = c & 31;
    const float* Wt = W_pre + t * 64 * 32 + half * 32 * 32;
    float wr[32];
#pragma unroll
    for (int k = 0; k < 32; ++k) wr[k] = Wt[k * 32 + o];
    float bp = half ? b_pre[t * 32 + o] : 0.f;
    __shared__ float sh[8][128];
    int base = blockIdx.x * NBP;
    for (int r = 0; r < NBP / 8; ++r) {
        int n0 = base + r * 8;
        __syncthreads();
        ((float4*)sh)[tid] = ((const float4*)(h + n0 * 128))[tid];   // 8 nodes staged
        __syncthreads();
        float acc[8];
#pragma unroll
        for (int ni = 0; ni < 8; ++ni) {
            const float4* h4 = (const float4*)(&sh[ni][t * 32]);
            float a = 0.f;
#pragma unroll
            for (int k4 = 0; k4 < 8; ++k4) {
                float4 hv = h4[k4];
                a = fmaf(hv.x, wr[4*k4+0], a);
                a = fmaf(hv.y, wr[4*k4+1], a);
                a = fmaf(hv.z, wr[4*k4+2], a);
                a = fmaf(hv.w, wr[4*k4+3], a);
            }
            acc[ni] = a;
        }
#pragma unroll
        for (int ni = 0; ni < 8; ++ni) {
            int n = n0 + ni;
            if (half) Pd[n * 128 + c] = __float2bfloat16(acc[ni] + bp);
            else      Ps[n * 128 + c] = __float2bfloat16(acc[ni]);
        }
    }
}

// ---------- K2: fused gather+stats -> LDS z -> MFMA posttrans+mix+residual ----------
// 16 nodes/block (exact), 256 threads (4 waves). LDS 25.1 KB -> 6 blocks/CU.
__global__ __launch_bounds__(256) void k_fused(const float* __restrict__ h,
        const int* __restrict__ src, const __hip_bfloat16* __restrict__ Pd,
        const __hip_bfloat16* __restrict__ Ps, const __hip_bfloat16* __restrict__ WeffT,
        const __hip_bfloat16* __restrict__ WmixT, const float* __restrict__ b_post,
        const float* __restrict__ b_mix, float* __restrict__ out) {
    // +8 row pad -> rows shift 4 banks; 16-row MFMA col reads alias 2-way (free)
    __shared__ __align__(16) __hip_bfloat16 sZ[NBF][648];
    __shared__ __align__(16) __hip_bfloat16 sHp[NBF][136];
    int tid = threadIdx.x, w = tid >> 6, lane = tid & 63;
    int nb = blockIdx.x * NBF;

    // ---- Phase A: stats straight into sZ; wave w owns rows {w, 4+w, 8+w, 12+w} ----
    int c0 = 2 * lane;                 // lane's channel pair
    int tA = c0 >> 5, oA = c0 & 31;
#pragma unroll
    for (int r = 0; r < 4; ++r) {
        int row = r * 4 + w;
        int n = nb + row;
        int vsrc = src[n * DEG + (lane & 31)];          // lanes 32-63 duplicate
        float2 hv = *(const float2*)(h + n * 128 + c0);
        unsigned int pdu = *(const unsigned int*)(Pd + n * 128 + c0);
        float pd0 = __uint_as_float(pdu << 16);
        float pd1 = __uint_as_float(pdu & 0xffff0000u);
        float sum0 = 0.f, sum1 = 0.f, sq0 = 0.f, sq1 = 0.f;
        float mx0 = -1e30f, mx1 = -1e30f, mn0 = 1e30f, mn1 = 1e30f;
#pragma unroll
        for (int j0 = 0; j0 < DEG; j0 += 8) {
            unsigned int pv[8];
#pragma unroll
            for (int u = 0; u < 8; ++u) {
                int s = __builtin_amdgcn_readlane(vsrc, j0 + u);
                pv[u] = *(const unsigned int*)(Ps + s * 128 + c0);
            }
#pragma unroll
            for (int u = 0; u < 8; ++u) {
                float f0 = __uint_as_float(pv[u] << 16);
                float f1 = __uint_as_float(pv[u] & 0xffff0000u);
                float e0 = fmaxf(f0 + pd0, 0.f);
                float e1 = fmaxf(f1 + pd1, 0.f);
                sum0 += e0; sq0 = fmaf(e0, e0, sq0);
                mx0 = fmaxf(mx0, e0); mn0 = fminf(mn0, e0);
                sum1 += e1; sq1 = fmaf(e1, e1, sq1);
                mx1 = fmaxf(mx1, e1); mn1 = fminf(mn1, e1);
            }
        }
        float mean0 = sum0 * (1.f / DEG), mean1 = sum1 * (1.f / DEG);
        float sd0 = sqrtf(fmaxf(sq0 * (1.f / DEG) - mean0 * mean0, 0.f) + EPSV);
        float sd1 = sqrtf(fmaxf(sq1 * (1.f / DEG) - mean1 * mean1, 0.f) + EPSV);
        unsigned int* zr = (unsigned int*)(&sZ[row][tA * 160 + oA]);  // 4B-aligned
        auto pack = [](float a, float b) {
            return (unsigned int)(__bfloat16_as_ushort(__float2bfloat16(a))) |
                   ((unsigned int)(__bfloat16_as_ushort(__float2bfloat16(b))) << 16);
        };
        zr[0]  = pack(hv.x, hv.y);
        zr[16] = pack(mean0, mean1);
        zr[32] = pack(mx0, mx1);
        zr[48] = pack(mn0, mn1);
        zr[64] = pack(sd0, sd1);
    }
    __syncthreads();

    // ---- Phase B: posttrans MFMA; 8 col-tiles over 4 waves (2 each) ----
    int col = lane & 15, quad = lane >> 4;
#pragma unroll
    for (int i = 0; i < 2; ++i) {
        int ct = w * 2 + i, t = ct >> 1, nt = ct & 1;
        f32x4 acc = {0.f, 0.f, 0.f, 0.f};
        int oc = t * 32 + nt * 16 + col;
        const __hip_bfloat16* wrow = WeffT + oc * 160 + quad * 8;
#pragma unroll
        for (int ks = 0; ks < 5; ++ks) {
            short8 a = *(const short8*)(&sZ[col][t * 160 + ks * 32 + quad * 8]);
            short8 b = *(const short8*)(wrow + ks * 32);
            acc = __builtin_amdgcn_mfma_f32_16x16x32_bf16(a, b, acc, 0, 0, 0);
        }
        float bp = b_post[oc];
#pragma unroll
        for (int r = 0; r < 4; ++r)
            sHp[quad * 4 + r][oc] = __float2bfloat16(fmaxf(acc[r] + bp, 0.f));
    }
    __syncthreads();

    // ---- Phase C: mix MFMA + leaky ReLU + residual ----
#pragma unroll
    for (int i = 0; i < 2; ++i) {
        int nt = w * 2 + i;
        f32x4 acc = {0.f, 0.f, 0.f, 0.f};
        int oc = nt * 16 + col;
        const __hip_bfloat16* wrow = WmixT + oc * 128 + quad * 8;
#pragma unroll
        for (int ks = 0; ks < 4; ++ks) {
            short8 a = *(const short8*)(&sHp[col][ks * 32 + quad * 8]);
            short8 b = *(const short8*)(wrow + ks * 32);
            acc = __builtin_amdgcn_mfma_f32_16x16x32_bf16(a, b, acc, 0, 0, 0);
        }
        float bm = b_mix[oc];
#pragma unroll
        for (int r = 0; r < 4; ++r) {
            int n = nb + quad * 4 + r;
            float m = acc[r] + bm;
            m = m > 0.f ? m : 0.01f * m;
            out[n * 128 + oc] = h[n * 128 + oc] + m;
        }
    }
}

extern "C" void kernel_launch(void* const* d_in, const int* in_sizes, int n_in,
                              void* d_out, int out_size, void* d_ws, size_t ws_size,
                              hipStream_t stream) {
    const float* h      = (const float*)d_in[0];
    const int*   src    = (const int*)d_in[1];
    // d_in[2] = dst: structurally repeat(arange(N), DEG) -> unused
    const float* W_pre  = (const float*)d_in[3];
    const float* b_pre  = (const float*)d_in[4];
    const float* W_post = (const float*)d_in[5];
    const float* b_post = (const float*)d_in[6];
    const float* W_mix  = (const float*)d_in[7];
    const float* b_mix  = (const float*)d_in[8];
    float* out = (float*)d_out;

    char* ws = (char*)d_ws;
    __hip_bfloat16* WeffT = (__hip_bfloat16*)ws;                      // 20480 bf16
    __hip_bfloat16* WmixT = (__hip_bfloat16*)(ws + 40960);            // 16384 bf16
    __hip_bfloat16* Pd    = (__hip_bfloat16*)(ws + 73728);            // N*128
    __hip_bfloat16* Ps    = (__hip_bfloat16*)(ws + 73728 + 12800000); // N*128

    double scd = log(33.0) / log(5.0);    // deg==32 constant
    float sc = (float)scd, isc = (float)(1.0 / scd);

    hipLaunchKernelGGL(k_prep, dim3(144), dim3(256), 0, stream, W_post, W_mix, WeffT, WmixT, sc, isc);
    hipLaunchKernelGGL(k_proj, dim3(N_NODES / NBP), dim3(256), 0, stream, h, W_pre, b_pre, Pd, Ps);
    hipLaunchKernelGGL(k_fused, dim3(N_NODES / NBF), dim3(256), 0, stream,
                       h, src, Pd, Ps, WeffT, WmixT, b_post, b_mix, out);
}

// Round 5
// 171.613 us; speedup vs baseline: 2.1857x; 1.0406x over previous
//
#include <hip/hip_runtime.h>
#include <hip/hip_bf16.h>
#include <math.h>

#define N_NODES 50000
#define DEG     32
#define NBF     16       // nodes/block k_fused (50000 = 3125*16)
#define EPSV    1e-5f

typedef __attribute__((ext_vector_type(8))) short short8;   // 8 bf16 (4 VGPRs)
typedef __attribute__((ext_vector_type(4))) float f32x4;
typedef __attribute__((ext_vector_type(2))) float f32x2;    // -> v_pk_*_f32

// ---------- K0: fold scalers + transpose + bf16-cast all weights ----------
// WeffT[t][o][k160], WmixT[o][k128], WpreT[p=t*2+half][o][k32]
__global__ void k_prep(const float* __restrict__ W_post, const float* __restrict__ W_mix,
                       const float* __restrict__ W_pre,
                       __hip_bfloat16* __restrict__ WeffT, __hip_bfloat16* __restrict__ WmixT,
                       __hip_bfloat16* __restrict__ WpreT, float sc, float isc) {
    int i = blockIdx.x * 256 + threadIdx.x;     // 176*256 = 45056 exact
    if (i < 20480) {
        int k = i % 160, to = i / 160, o = to & 31, t = to >> 5;
        const float* Wt = W_post + t * 416 * 32;
        float v;
        if (k < 32) v = Wt[k * 32 + o];
        else {
            int g = k - 32;   // [mean,mx,mn,std]; fold identity+amp+att (deg==32 const)
            v = Wt[(32 + g) * 32 + o] + sc * Wt[(160 + g) * 32 + o] + isc * Wt[(288 + g) * 32 + o];
        }
        WeffT[i] = __float2bfloat16(v);
    } else if (i < 36864) {
        int j = i - 20480;
        int k = j & 127, o = j >> 7;
        WmixT[j] = __float2bfloat16(W_mix[k * 128 + o]);
    } else if (i < 45056) {
        int q = i - 36864;                       // p<<10 | o<<5 | k
        int k = q & 31, o = (q >> 5) & 31, p = q >> 10;
        int t = p >> 1, half = p & 1;
        WpreT[q] = __float2bfloat16(W_pre[t * 2048 + (half * 32 + k) * 32 + o]);
    }
}

// ---------- K1: pretrans projections via MFMA (8 GEMMs M=N_NODES,K=32,N=32) ----------
// 64 nodes/block, 4 waves each own 16 node rows; K=32 -> 1 MFMA per 16x16 tile.
__global__ __launch_bounds__(256) void k_proj(const float* __restrict__ h,
        const __hip_bfloat16* __restrict__ WpreT, const float* __restrict__ b_pre,
        __hip_bfloat16* __restrict__ Pd, __hip_bfloat16* __restrict__ Ps) {
    __shared__ __align__(16) __hip_bfloat16 sA[64][136];   // +8 pad: 2-way alias only
    int tid = threadIdx.x, w = tid >> 6, lane = tid & 63;
    int nb = blockIdx.x * 64;

    // stage h -> bf16 LDS: thread handles 4 ch x 8 rows
    int colc = (tid & 31) * 4, rowb = tid >> 5;
#pragma unroll
    for (int i = 0; i < 8; ++i) {
        int row = i * 8 + rowb;
        int n = nb + row;
        unsigned int lo = 0, hi = 0;
        if (n < N_NODES) {
            float4 f = *(const float4*)(h + n * 128 + colc);
            lo = (unsigned int)__bfloat16_as_ushort(__float2bfloat16(f.x)) |
                 ((unsigned int)__bfloat16_as_ushort(__float2bfloat16(f.y)) << 16);
            hi = (unsigned int)__bfloat16_as_ushort(__float2bfloat16(f.z)) |
                 ((unsigned int)__bfloat16_as_ushort(__float2bfloat16(f.w)) << 16);
        }
        *(uint2*)(&sA[row][colc]) = make_uint2(lo, hi);
    }
    __syncthreads();

    int col = lane & 15, quad = lane >> 4;
    int r0 = w * 16;
    short8 a[4];
#pragma unroll
    for (int t = 0; t < 4; ++t)
        a[t] = *(const short8*)(&sA[r0 + col][t * 32 + quad * 8]);

#pragma unroll
    for (int p = 0; p < 8; ++p) {
        int t = p >> 1, isPd = p & 1;
#pragma unroll
        for (int ct = 0; ct < 2; ++ct) {
            int o = ct * 16 + col;              // within-tower out channel
            short8 b = *(const short8*)(WpreT + p * 1024 + o * 32 + quad * 8);
            f32x4 acc = {0.f, 0.f, 0.f, 0.f};
            acc = __builtin_amdgcn_mfma_f32_16x16x32_bf16(a[t], b, acc, 0, 0, 0);
            float bp = isPd ? b_pre[t * 32 + o] : 0.f;
            __hip_bfloat16* dst = (isPd ? Pd : Ps);
#pragma unroll
            for (int r = 0; r < 4; ++r) {
                int n = nb + r0 + quad * 4 + r;
                if (n < N_NODES)
                    dst[n * 128 + t * 32 + o] = __float2bfloat16(acc[r] + bp);
            }
        }
    }
}

// ---------- K2: fused gather+stats (packed f32) -> LDS z -> MFMA post+mix ----------
__global__ __launch_bounds__(256) void k_fused(const float* __restrict__ h,
        const int* __restrict__ src, const __hip_bfloat16* __restrict__ Pd,
        const __hip_bfloat16* __restrict__ Ps, const __hip_bfloat16* __restrict__ WeffT,
        const __hip_bfloat16* __restrict__ WmixT, const float* __restrict__ b_post,
        const float* __restrict__ b_mix, float* __restrict__ out) {
    __shared__ __align__(16) __hip_bfloat16 sZ[NBF][648];
    __shared__ __align__(16) __hip_bfloat16 sHp[NBF][136];
    int tid = threadIdx.x, w = tid >> 6, lane = tid & 63;
    int nb = blockIdx.x * NBF;

    // ---- Phase A: stats straight into sZ; wave w owns rows {w,4+w,8+w,12+w} ----
    int c0 = 2 * lane;
    int tA = c0 >> 5, oA = c0 & 31;
    const f32x2 zero2 = {0.f, 0.f};
#pragma unroll
    for (int r = 0; r < 4; ++r) {
        int row = r * 4 + w;
        int n = nb + row;
        int vsrc = src[n * DEG + (lane & 31)];          // lanes 32-63 duplicate
        float2 hv = *(const float2*)(h + n * 128 + c0);
        unsigned int pdu = *(const unsigned int*)(Pd + n * 128 + c0);
        f32x2 pd2 = {__uint_as_float(pdu << 16), __uint_as_float(pdu & 0xffff0000u)};
        f32x2 sum = zero2, sq = zero2;
        f32x2 mx = {-1e30f, -1e30f}, mn = {1e30f, 1e30f};
#pragma unroll
        for (int j0 = 0; j0 < DEG; j0 += 16) {          // 16 loads in flight
            unsigned int pv[16];
#pragma unroll
            for (int u = 0; u < 16; ++u) {
                int s = __builtin_amdgcn_readlane(vsrc, j0 + u);
                pv[u] = *(const unsigned int*)(Ps + s * 128 + c0);
            }
#pragma unroll
            for (int u = 0; u < 16; ++u) {
                f32x2 f = {__uint_as_float(pv[u] << 16),
                           __uint_as_float(pv[u] & 0xffff0000u)};
                f32x2 e = __builtin_elementwise_max(f + pd2, zero2);  // v_pk_add+pk_max
                sum += e;
                sq = e * e + sq;                                      // -> v_pk_fma
                mx = __builtin_elementwise_max(mx, e);
                mn = __builtin_elementwise_min(mn, e);
            }
        }
        f32x2 mean = sum * (1.f / DEG);
        f32x2 var = sq * (1.f / DEG) - mean * mean;
        float sd0 = sqrtf(fmaxf(var.x, 0.f) + EPSV);
        float sd1 = sqrtf(fmaxf(var.y, 0.f) + EPSV);
        unsigned int* zr = (unsigned int*)(&sZ[row][tA * 160 + oA]);
        auto pack = [](float a, float b) {
            return (unsigned int)(__bfloat16_as_ushort(__float2bfloat16(a))) |
                   ((unsigned int)(__bfloat16_as_ushort(__float2bfloat16(b))) << 16);
        };
        zr[0]  = pack(hv.x, hv.y);
        zr[16] = pack(mean.x, mean.y);
        zr[32] = pack(mx.x, mx.y);
        zr[48] = pack(mn.x, mn.y);
        zr[64] = pack(sd0, sd1);
    }
    __syncthreads();

    // ---- Phase B: posttrans MFMA; 8 col-tiles over 4 waves (2 each) ----
    int col = lane & 15, quad = lane >> 4;
#pragma unroll
    for (int i = 0; i < 2; ++i) {
        int ct = w * 2 + i, t = ct >> 1, nt = ct & 1;
        f32x4 acc = {0.f, 0.f, 0.f, 0.f};
        int oc = t * 32 + nt * 16 + col;
        const __hip_bfloat16* wrow = WeffT + oc * 160 + quad * 8;
#pragma unroll
        for (int ks = 0; ks < 5; ++ks) {
            short8 a = *(const short8*)(&sZ[col][t * 160 + ks * 32 + quad * 8]);
            short8 b = *(const short8*)(wrow + ks * 32);
            acc = __builtin_amdgcn_mfma_f32_16x16x32_bf16(a, b, acc, 0, 0, 0);
        }
        float bp = b_post[oc];
#pragma unroll
        for (int r = 0; r < 4; ++r)
            sHp[quad * 4 + r][oc] = __float2bfloat16(fmaxf(acc[r] + bp, 0.f));
    }
    __syncthreads();

    // ---- Phase C: mix MFMA + leaky ReLU + residual ----
#pragma unroll
    for (int i = 0; i < 2; ++i) {
        int nt = w * 2 + i;
        f32x4 acc = {0.f, 0.f, 0.f, 0.f};
        int oc = nt * 16 + col;
        const __hip_bfloat16* wrow = WmixT + oc * 128 + quad * 8;
#pragma unroll
        for (int ks = 0; ks < 4; ++ks) {
            short8 a = *(const short8*)(&sHp[col][ks * 32 + quad * 8]);
            short8 b = *(const short8*)(wrow + ks * 32);
            acc = __builtin_amdgcn_mfma_f32_16x16x32_bf16(a, b, acc, 0, 0, 0);
        }
        float bm = b_mix[oc];
#pragma unroll
        for (int r = 0; r < 4; ++r) {
            int n = nb + quad * 4 + r;
            float m = acc[r] + bm;
            m = m > 0.f ? m : 0.01f * m;
            out[n * 128 + oc] = h[n * 128 + oc] + m;
        }
    }
}

extern "C" void kernel_launch(void* const* d_in, const int* in_sizes, int n_in,
                              void* d_out, int out_size, void* d_ws, size_t ws_size,
                              hipStream_t stream) {
    const float* h      = (const float*)d_in[0];
    const int*   src    = (const int*)d_in[1];
    // d_in[2] = dst: structurally repeat(arange(N), DEG) -> unused
    const float* W_pre  = (const float*)d_in[3];
    const float* b_pre  = (const float*)d_in[4];
    const float* W_post = (const float*)d_in[5];
    const float* b_post = (const float*)d_in[6];
    const float* W_mix  = (const float*)d_in[7];
    const float* b_mix  = (const float*)d_in[8];
    float* out = (float*)d_out;

    char* ws = (char*)d_ws;
    __hip_bfloat16* WeffT = (__hip_bfloat16*)ws;                      // 20480 bf16
    __hip_bfloat16* WmixT = (__hip_bfloat16*)(ws + 40960);            // 16384 bf16
    __hip_bfloat16* WpreT = (__hip_bfloat16*)(ws + 73728);            // 8192 bf16
    __hip_bfloat16* Pd    = (__hip_bfloat16*)(ws + 90112);            // N*128
    __hip_bfloat16* Ps    = (__hip_bfloat16*)(ws + 90112 + 12800000); // N*128

    double scd = log(33.0) / log(5.0);    // deg==32 constant
    float sc = (float)scd, isc = (float)(1.0 / scd);

    hipLaunchKernelGGL(k_prep, dim3(176), dim3(256), 0, stream,
                       W_post, W_mix, W_pre, WeffT, WmixT, WpreT, sc, isc);
    hipLaunchKernelGGL(k_proj, dim3((N_NODES + 63) / 64), dim3(256), 0, stream,
                       h, WpreT, b_pre, Pd, Ps);
    hipLaunchKernelGGL(k_fused, dim3(N_NODES / NBF), dim3(256), 0, stream,
                       h, src, Pd, Ps, WeffT, WmixT, b_post, b_mix, out);
}

// Round 7
// 164.398 us; speedup vs baseline: 2.2816x; 1.0439x over previous
//
#include <hip/hip_runtime.h>
#include <hip/hip_bf16.h>
#include <hip/hip_fp16.h>
#include <math.h>

#define N_NODES 50000
#define DEG     32
#define NBF     16       // nodes/block k_fused (50000 = 3125*16)
#define EPSV    1e-5f

typedef __attribute__((ext_vector_type(8))) short short8;   // 8 bf16 (4 VGPRs)
typedef __attribute__((ext_vector_type(4))) float f32x4;
typedef __attribute__((ext_vector_type(2))) _Float16 h16x2; // -> v_pk_*_f16
typedef __attribute__((ext_vector_type(4))) unsigned int uint4v;

__device__ __forceinline__ unsigned int bfpack(float a, float b) {
    return (unsigned int)__bfloat16_as_ushort(__float2bfloat16(a)) |
           ((unsigned int)__bfloat16_as_ushort(__float2bfloat16(b)) << 16);
}

// ---------- K1: weight prep (first 144 blocks) + pretrans MFMA -> Ps/Pd f16 ----------
// 64 nodes/block; B-fragments built per-thread from L2-resident W_pre (no WpreT).
__global__ __launch_bounds__(256) void k_proj(const float* __restrict__ h,
        const float* __restrict__ W_pre, const float* __restrict__ b_pre,
        const float* __restrict__ W_post, const float* __restrict__ W_mix,
        __hip_bfloat16* __restrict__ WeffT, __hip_bfloat16* __restrict__ WmixT,
        _Float16* __restrict__ Pd, _Float16* __restrict__ Ps, float sc, float isc) {
    int tid = threadIdx.x, w = tid >> 6, lane = tid & 63;
    int nb = blockIdx.x * 64;

    // merged k_prep: fold scalers into WeffT, transpose WmixT (consumed by k_fused only)
    if (blockIdx.x < 144) {
        int i = blockIdx.x * 256 + tid;          // 36864 exact
        if (i < 20480) {
            int k = i % 160, to = i / 160, o = to & 31, t = to >> 5;
            const float* Wt = W_post + t * 416 * 32;
            float v;
            if (k < 32) v = Wt[k * 32 + o];
            else {
                int g = k - 32;   // [mean,mx,mn,std]; identity+amp+att folded (deg==32)
                v = Wt[(32 + g) * 32 + o] + sc * Wt[(160 + g) * 32 + o]
                  + isc * Wt[(288 + g) * 32 + o];
            }
            WeffT[i] = __float2bfloat16(v);
        } else {
            int j = i - 20480;
            int k = j & 127, o = j >> 7;
            WmixT[j] = __float2bfloat16(W_mix[k * 128 + o]);
        }
    }

    __shared__ __align__(16) __hip_bfloat16 sA[64][136];   // +8 pad
    // stage h -> bf16 LDS
    int colc = (tid & 31) * 4, rowb = tid >> 5;
#pragma unroll
    for (int i = 0; i < 8; ++i) {
        int row = i * 8 + rowb, n = nb + row;
        unsigned int lo = 0, hi = 0;
        if (n < N_NODES) {
            float4 f = *(const float4*)(h + n * 128 + colc);
            lo = bfpack(f.x, f.y); hi = bfpack(f.z, f.w);
        }
        *(uint2*)(&sA[row][colc]) = make_uint2(lo, hi);
    }
    __syncthreads();
    int col = lane & 15, quad = lane >> 4, r0 = w * 16;
    short8 a[4];
#pragma unroll
    for (int t = 0; t < 4; ++t)
        a[t] = *(const short8*)(&sA[r0 + col][t * 32 + quad * 8]);
    __syncthreads();     // sA reused as output-transpose buffer (f16 bits)
    unsigned short* sOut = (unsigned short*)sA;   // [64][136]

#pragma unroll
    for (int half = 0; half < 2; ++half) {       // 0: Ps, 1: Pd(+bias)
#pragma unroll
        for (int t = 0; t < 4; ++t) {
#pragma unroll
            for (int ct = 0; ct < 2; ++ct) {
                int o = ct * 16 + col;
                // build B fragment from W_pre rows (half*32+quad*8 .. +7), col o
                const float* wp = W_pre + t * 2048 + (half * 32 + quad * 8) * 32 + o;
                unsigned int bw0 = bfpack(wp[0],   wp[32]);
                unsigned int bw1 = bfpack(wp[64],  wp[96]);
                unsigned int bw2 = bfpack(wp[128], wp[160]);
                unsigned int bw3 = bfpack(wp[192], wp[224]);
                uint4v bwv = {bw0, bw1, bw2, bw3};
                short8 b = __builtin_bit_cast(short8, bwv);
                f32x4 acc = {0.f, 0.f, 0.f, 0.f};
                acc = __builtin_amdgcn_mfma_f32_16x16x32_bf16(a[t], b, acc, 0, 0, 0);
                float bp = half ? b_pre[t * 32 + o] : 0.f;
#pragma unroll
                for (int r = 0; r < 4; ++r)
                    sOut[(r0 + quad * 4 + r) * 136 + t * 32 + o] =
                        __half_as_ushort(__float2half(acc[r] + bp));
            }
        }
        __syncthreads();
        _Float16* dst = half ? Pd : Ps;
        // coalesced stores: 64 rows x 16 segs of 8 f16 (16B); 4 rounds
#pragma unroll
        for (int rr = 0; rr < 4; ++rr) {
            int chunk = rr * 256 + tid;
            int row = chunk >> 4, seg = chunk & 15, n = nb + row;
            if (n < N_NODES)
                *(uint4v*)(dst + n * 128 + seg * 8) =
                    *(const uint4v*)(&sOut[row * 136 + seg * 8]);
        }
        __syncthreads();
    }
}

// ---------- K2: fused gather(f16, packed stats) -> LDS z -> MFMA post+mix ----------
__global__ __launch_bounds__(256) void k_fused(const float* __restrict__ h,
        const int* __restrict__ src, const _Float16* __restrict__ Pd,
        const _Float16* __restrict__ Ps, const __hip_bfloat16* __restrict__ WeffT,
        const __hip_bfloat16* __restrict__ WmixT, const float* __restrict__ b_post,
        const float* __restrict__ b_mix, float* __restrict__ out) {
    __shared__ __align__(16) __hip_bfloat16 sZ[NBF][648];
    __shared__ __align__(16) __hip_bfloat16 sHp[NBF][136];
    int tid = threadIdx.x, w = tid >> 6, lane = tid & 63;
    int nb = blockIdx.x * NBF;

    // ---- Phase A: 2 node rows per wave-iter (half-wave each), 4 ch/lane, pk-f16 ----
    int lid = lane & 31, hsel = lane & 32;
    int cq = lid * 4;
    int tA = cq >> 5, oA = cq & 31;
    const h16x2 zeroh = {(_Float16)0.f, (_Float16)0.f};
    const h16x2 bigh  = {(_Float16)65504.f, (_Float16)65504.f};
#pragma unroll
    for (int it = 0; it < 2; ++it) {
        int row = it * 8 + w + (hsel >> 3);         // upper half-wave: +4
        int n = nb + row;
        int vsrc = src[n * DEG + lid];
        float4 hv = *(const float4*)(h + n * 128 + cq);
        uint2 pdu = *(const uint2*)(Pd + n * 128 + cq);
        h16x2 pd01 = __builtin_bit_cast(h16x2, pdu.x);
        h16x2 pd23 = __builtin_bit_cast(h16x2, pdu.y);
        h16x2 sum01 = zeroh, sum23 = zeroh, sq01 = zeroh, sq23 = zeroh;
        h16x2 mx01 = zeroh, mx23 = zeroh;           // e >= 0, so 0 is a valid floor
        h16x2 mn01 = bigh, mn23 = bigh;
#pragma unroll
        for (int j0 = 0; j0 < DEG; j0 += 16) {
            uint2 pv[16];
#pragma unroll
            for (int u = 0; u < 16; ++u) {
                int s = __shfl(vsrc, (j0 + u) | hsel);
                pv[u] = *(const uint2*)(Ps + s * 128 + cq);
            }
#pragma unroll
            for (int u = 0; u < 16; ++u) {
                h16x2 f01 = __builtin_bit_cast(h16x2, pv[u].x);
                h16x2 f23 = __builtin_bit_cast(h16x2, pv[u].y);
                h16x2 e01 = __builtin_elementwise_max(f01 + pd01, zeroh);
                h16x2 e23 = __builtin_elementwise_max(f23 + pd23, zeroh);
                sum01 += e01; sq01 = e01 * e01 + sq01;
                mx01 = __builtin_elementwise_max(mx01, e01);
                mn01 = __builtin_elementwise_min(mn01, e01);
                sum23 += e23; sq23 = e23 * e23 + sq23;
                mx23 = __builtin_elementwise_max(mx23, e23);
                mn23 = __builtin_elementwise_min(mn23, e23);
            }
        }
        float mean0 = (float)sum01.x * (1.f / DEG), mean1 = (float)sum01.y * (1.f / DEG);
        float mean2 = (float)sum23.x * (1.f / DEG), mean3 = (float)sum23.y * (1.f / DEG);
        float sd0 = sqrtf(fmaxf((float)sq01.x * (1.f / DEG) - mean0 * mean0, 0.f) + EPSV);
        float sd1 = sqrtf(fmaxf((float)sq01.y * (1.f / DEG) - mean1 * mean1, 0.f) + EPSV);
        float sd2 = sqrtf(fmaxf((float)sq23.x * (1.f / DEG) - mean2 * mean2, 0.f) + EPSV);
        float sd3 = sqrtf(fmaxf((float)sq23.y * (1.f / DEG) - mean3 * mean3, 0.f) + EPSV);
        unsigned int* zr = (unsigned int*)(&sZ[row][tA * 160 + oA]);
        zr[0]  = bfpack(hv.x, hv.y);               zr[1]  = bfpack(hv.z, hv.w);
        zr[16] = bfpack(mean0, mean1);             zr[17] = bfpack(mean2, mean3);
        zr[32] = bfpack((float)mx01.x, (float)mx01.y);
        zr[33] = bfpack((float)mx23.x, (float)mx23.y);
        zr[48] = bfpack((float)mn01.x, (float)mn01.y);
        zr[49] = bfpack((float)mn23.x, (float)mn23.y);
        zr[64] = bfpack(sd0, sd1);                 zr[65] = bfpack(sd2, sd3);
    }
    __syncthreads();

    // ---- Phase B: posttrans MFMA; 8 col-tiles over 4 waves (2 each) ----
    int col = lane & 15, quad = lane >> 4;
#pragma unroll
    for (int i = 0; i < 2; ++i) {
        int ct = w * 2 + i, t = ct >> 1, nt = ct & 1;
        f32x4 acc = {0.f, 0.f, 0.f, 0.f};
        int oc = t * 32 + nt * 16 + col;
        const __hip_bfloat16* wrow = WeffT + oc * 160 + quad * 8;
#pragma unroll
        for (int ks = 0; ks < 5; ++ks) {
            short8 a = *(const short8*)(&sZ[col][t * 160 + ks * 32 + quad * 8]);
            short8 b = *(const short8*)(wrow + ks * 32);
            acc = __builtin_amdgcn_mfma_f32_16x16x32_bf16(a, b, acc, 0, 0, 0);
        }
        float bp = b_post[oc];
#pragma unroll
        for (int r = 0; r < 4; ++r)
            sHp[quad * 4 + r][oc] = __float2bfloat16(fmaxf(acc[r] + bp, 0.f));
    }
    __syncthreads();

    // ---- Phase C: mix MFMA + leaky ReLU + residual ----
#pragma unroll
    for (int i = 0; i < 2; ++i) {
        int nt = w * 2 + i;
        f32x4 acc = {0.f, 0.f, 0.f, 0.f};
        int oc = nt * 16 + col;
        const __hip_bfloat16* wrow = WmixT + oc * 128 + quad * 8;
#pragma unroll
        for (int ks = 0; ks < 4; ++ks) {
            short8 a = *(const short8*)(&sHp[col][ks * 32 + quad * 8]);
            short8 b = *(const short8*)(wrow + ks * 32);
            acc = __builtin_amdgcn_mfma_f32_16x16x32_bf16(a, b, acc, 0, 0, 0);
        }
        float bm = b_mix[oc];
#pragma unroll
        for (int r = 0; r < 4; ++r) {
            int n = nb + quad * 4 + r;
            float m = acc[r] + bm;
            m = m > 0.f ? m : 0.01f * m;
            out[n * 128 + oc] = h[n * 128 + oc] + m;
        }
    }
}

extern "C" void kernel_launch(void* const* d_in, const int* in_sizes, int n_in,
                              void* d_out, int out_size, void* d_ws, size_t ws_size,
                              hipStream_t stream) {
    const float* h      = (const float*)d_in[0];
    const int*   src    = (const int*)d_in[1];
    // d_in[2] = dst: structurally repeat(arange(N), DEG) -> unused
    const float* W_pre  = (const float*)d_in[3];
    const float* b_pre  = (const float*)d_in[4];
    const float* W_post = (const float*)d_in[5];
    const float* b_post = (const float*)d_in[6];
    const float* W_mix  = (const float*)d_in[7];
    const float* b_mix  = (const float*)d_in[8];
    float* out = (float*)d_out;

    char* ws = (char*)d_ws;
    __hip_bfloat16* WeffT = (__hip_bfloat16*)ws;                      // 20480 bf16
    __hip_bfloat16* WmixT = (__hip_bfloat16*)(ws + 40960);            // 16384 bf16
    _Float16*       Pd    = (_Float16*)(ws + 81920);                  // N*128 f16
    _Float16*       Ps    = (_Float16*)(ws + 81920 + 12800000);       // N*128 f16

    double scd = log(33.0) / log(5.0);    // deg==32 constant
    float sc = (float)scd, isc = (float)(1.0 / scd);

    hipLaunchKernelGGL(k_proj, dim3((N_NODES + 63) / 64), dim3(256), 0, stream,
                       h, W_pre, b_pre, W_post, W_mix, WeffT, WmixT, Pd, Ps, sc, isc);
    hipLaunchKernelGGL(k_fused, dim3(N_NODES / NBF), dim3(256), 0, stream,
                       h, src, Pd, Ps, WeffT, WmixT, b_post, b_mix, out);
}